// Round 14
// baseline (39.409 us; speedup 1.0000x reference)
//
#include <hip/hip_runtime.h>
#include <hip/hip_bf16.h>
#include <stdint.h>

// Mahalanobis: out[i] = delta_i @ S_inv @ delta_i^T, delta = x - x_fit
// N=65536, D=256.
// Round 12 -> 13: OCCUPANCY lever (last untested). All prior nulls ran at
// 16 waves/CU (50%), pinned by 64-reg S frags + staging regs; r5 showed BW
// tracks wave count. Now: 1024-thread blocks, 16 waves x 16-col S slices
// (32 frag regs), staging via global_load_lds (ZERO staging registers,
// f32 rows DMA'd straight to LDS) -> ~50 regs, __launch_bounds__(1024,8)
// -> 32 waves/CU (100% occupancy), 2 blocks/CU, LDS 76.3KB/block.
// Convert phase reads f32 from LDS -> bf16 tile; epilogue delta in f32.
// Fused S-convert abandoned for good (spilled twice: r7, r12).

#define D 256
#define BLOCK_T 1024          // 16 waves
#define RPT 16                // rows per tile
#define NT 8                  // 128 rows/block; grid = 65536/128 = 512
#define BSTR 260              // f32 LDS row stride (words); 260%32=4 -> 2-way max
#define TSTR 272              // bf16 tile row stride (shorts)

typedef __attribute__((ext_vector_type(4))) float f32x4;
typedef __attribute__((ext_vector_type(8))) short bf16x8;
typedef __attribute__((ext_vector_type(4))) short bf16x4;

static __device__ __forceinline__ unsigned short f2bf(float f) {
    union { float f; uint32_t u; } v; v.f = f;
    uint32_t u = v.u;
    return (unsigned short)((u + 0x7FFFu + ((u >> 16) & 1u)) >> 16);
}

// DMA one 16B/lane chunk global->LDS (wave-uniform LDS base + lane*16).
static __device__ __forceinline__ void gload_lds16(const float* g, void* l) {
    __builtin_amdgcn_global_load_lds(
        (const __attribute__((address_space(1))) void*)g,
        (__attribute__((address_space(3))) void*)l, 16, 0, 0);
}

// S_inv fp32 -> bf16 (row-major; S is symmetric so this is also S^T)
__global__ void prep_S_kernel(const float* __restrict__ S, unsigned short* __restrict__ Sb) {
    int i = (blockIdx.x * 256 + threadIdx.x) * 4;
    f32x4 v = *(const f32x4*)(S + i);
    uint32_t lo = (uint32_t)f2bf(v[0]) | ((uint32_t)f2bf(v[1]) << 16);
    uint32_t hi = (uint32_t)f2bf(v[2]) | ((uint32_t)f2bf(v[3]) << 16);
    *(uint2*)(Sb + i) = make_uint2(lo, hi);
}

__global__ __launch_bounds__(BLOCK_T, 8) void mahal_kernel(
    const float* __restrict__ x, const float* __restrict__ xf,
    const unsigned short* __restrict__ Sb, float* __restrict__ out)
{
    __shared__ float xb[2][RPT][BSTR];            // 33280 B
    __shared__ float fb[2][RPT][BSTR];            // 33280 B
    __shared__ unsigned short ld[RPT * TSTR];     //  8704 B
    __shared__ float psum[16 * RPT];              //  1024 B -> 76288 B total

    const int t    = threadIdx.x;
    const int w    = t >> 6;      // wave 0..15: owns S cols [w*16, w*16+16)
    const int lane = t & 63;
    const int lo4  = lane & 15;
    const int kg   = lane >> 4;   // k-group 0..3
    const int blockRow0 = blockIdx.x * (NT * RPT);

    // ---- S fragments: 16-col slice, bf16 plain loads (32 VGPRs).
    // A-operand: A[i][k] = S[w*16 + i][k] (S symmetric).
    bf16x8 b[8];
    {
        const unsigned short* Sp = Sb + (w * 16 + lo4) * D + kg * 8;
        #pragma unroll
        for (int kb = 0; kb < 8; ++kb) b[kb] = *(const bf16x8*)(Sp + kb * 32);
    }

    // ---- prologue: DMA tile 0 (wave w stages x-row w and xf-row w) ----
    gload_lds16(x  + (blockRow0 + w) * D + lane * 4, &xb[0][w][0]);
    gload_lds16(xf + (blockRow0 + w) * D + lane * 4, &fb[0][w][0]);

    #pragma unroll
    for (int j = 0; j < NT; ++j) {
        const int cur = j & 1, nxt = cur ^ 1;

        // tile j's DMA landed (all waves after barrier); psum(j-1) visible
        asm volatile("s_waitcnt vmcnt(0) lgkmcnt(0)" ::: "memory");
        __builtin_amdgcn_sched_barrier(0);
        __builtin_amdgcn_s_barrier();

        // ---- prefetch tile j+1: DMA flies under convert+compute of j.
        // xb[nxt]'s last readers (tile j-1) all finished before the barrier.
        if (j + 1 < NT) {
            gload_lds16(x  + (blockRow0 + (j + 1) * RPT + w) * D + lane * 4, &xb[nxt][w][0]);
            gload_lds16(xf + (blockRow0 + (j + 1) * RPT + w) * D + lane * 4, &fb[nxt][w][0]);
        }

        // ---- combine tile j-1 partials ----
        if (j > 0 && t < RPT) {
            float s = 0.f;
            #pragma unroll
            for (int ww = 0; ww < 16; ++ww) s += psum[ww * RPT + t];
            out[blockRow0 + (j - 1) * RPT + t] = s;
        }

        // ---- convert tile j: f32 LDS -> bf16 delta tile (4 elems/thread) ----
        {
            const int cr = t >> 6;          // row 0..15 (== w)
            const int cc = (t & 63) * 4;    // col 0..252
            f32x4 xv = *(const f32x4*)&xb[cur][cr][cc];
            f32x4 fv = *(const f32x4*)&fb[cur][cr][cc];
            bf16x4 o;
            o[0] = (short)f2bf(xv[0] - fv[0]);
            o[1] = (short)f2bf(xv[1] - fv[1]);
            o[2] = (short)f2bf(xv[2] - fv[2]);
            o[3] = (short)f2bf(xv[3] - fv[3]);
            *(bf16x4*)&ld[cr * TSTR + cc] = o;
        }

        // bf16 tile visible; NO vmcnt drain here (prefetch stays in flight)
        asm volatile("s_waitcnt lgkmcnt(0)" ::: "memory");
        __builtin_amdgcn_s_barrier();
        __builtin_amdgcn_sched_barrier(0);

        // ---- compute tile j: T^T for this wave's 16-col slice ----
        {
            f32x4 acc = (f32x4){0.f, 0.f, 0.f, 0.f};
            #pragma unroll
            for (int kb = 0; kb < 8; ++kb) {
                bf16x8 a = *(const bf16x8*)&ld[lo4 * TSTR + kb * 32 + kg * 8];
                // swapped operands: D[i][r] = sum_k S[w*16+i][k]*delta[row_r][k]
                acc = __builtin_amdgcn_mfma_f32_16x16x32_bf16(b[kb], a, acc, 0, 0, 0);
            }
            // lane lo4 = delta row; reg r = T[drow][w*16 + kg*4 + r];
            // epilogue delta read in f32 from the staged buffers
            f32x4 dx = *(const f32x4*)&xb[cur][lo4][w * 16 + kg * 4];
            f32x4 df = *(const f32x4*)&fb[cur][lo4][w * 16 + kg * 4];
            float pr = 0.f;
            #pragma unroll
            for (int r = 0; r < 4; ++r) pr += acc[r] * (dx[r] - df[r]);
            // reduce over the 4 k-groups holding the same delta row
            pr += __shfl_xor(pr, 16, 64);
            pr += __shfl_xor(pr, 32, 64);
            if (lane < 16) psum[w * RPT + lane] = pr;
        }
    }

    // ---- final tile's combine ----
    asm volatile("s_waitcnt lgkmcnt(0)" ::: "memory");
    __builtin_amdgcn_s_barrier();
    if (t < RPT) {
        float s = 0.f;
        #pragma unroll
        for (int ww = 0; ww < 16; ++ww) s += psum[ww * RPT + t];
        out[blockRow0 + (NT - 1) * RPT + t] = s;
    }
}

extern "C" void kernel_launch(void* const* d_in, const int* in_sizes, int n_in,
                              void* d_out, int out_size, void* d_ws, size_t ws_size,
                              hipStream_t stream) {
    const float* x  = (const float*)d_in[0];
    const float* xf = (const float*)d_in[1];
    const float* S  = (const float*)d_in[2];
    float* out = (float*)d_out;
    unsigned short* Sb = (unsigned short*)d_ws;  // 65536 * 2B = 128 KB scratch

    prep_S_kernel<<<(D * D) / (256 * 4), 256, 0, stream>>>(S, Sb);

    const int nRows = in_sizes[0] / D;                 // 65536
    const int nBlocks = nRows / (NT * RPT);            // 512
    mahal_kernel<<<nBlocks, BLOCK_T, 0, stream>>>(x, xf, Sb, out);
}

// Round 15
// 34.076 us; speedup vs baseline: 1.1565x; 1.1565x over previous
//
#include <hip/hip_runtime.h>
#include <hip/hip_bf16.h>
#include <stdint.h>

// Mahalanobis: out[i] = delta_i @ S_inv @ delta_i^T, delta = x - x_fit
// N=65536, D=256.
// Round 14 -> 15: REVERT to round 11 (best measured: 33.5us). The occupancy
// probe (r14: 66% occ, 39.4us) falsified the last untested lever - effective
// streaming read BW (~4.3 TB/s at this ~50% L3-hit mix) is invariant to
// coalescing (r9), TLP x pipelining (r8), counted-vmcnt depth (r11), and
// occupancy (r14). It is an outstanding-line-capacity x latency bound in
// the memory path, not addressable from HIP source. Compute pipes idle
// (MFMA 6%, VALU 8%): this op is memory-path-bound at ~4.3 TB/s effective.

#define D 256
#define BLOCK_T 512           // 8 waves
#define RPT 16                // rows per tile
#define NT 8                  // 128 rows/block; grid = 65536/128 = 512
#define LDS_STRIDE 272

typedef __attribute__((ext_vector_type(4))) float f32x4;
typedef __attribute__((ext_vector_type(8))) short bf16x8;
typedef __attribute__((ext_vector_type(4))) short bf16x4;

static __device__ __forceinline__ unsigned short f2bf(float f) {
    union { float f; uint32_t u; } v; v.f = f;
    uint32_t u = v.u;
    return (unsigned short)((u + 0x7FFFu + ((u >> 16) & 1u)) >> 16);
}
static __device__ __forceinline__ float bf2f(unsigned short s) {
    union { uint32_t u; float f; } v; v.u = ((uint32_t)s) << 16;
    return v.f;
}

// Opaque 16B global load: fixed issue point (cannot be sunk to its use).
static __device__ __forceinline__ f32x4 gload4f(const float* p) {
    f32x4 r;
    asm volatile("global_load_dwordx4 %0, %1, off" : "=v"(r) : "v"(p));
    return r;
}

// S_inv fp32 -> bf16 (row-major; S is symmetric so this is also S^T)
__global__ void prep_S_kernel(const float* __restrict__ S, unsigned short* __restrict__ Sb) {
    int i = (blockIdx.x * 256 + threadIdx.x) * 4;
    f32x4 v = *(const f32x4*)(S + i);
    uint32_t lo = (uint32_t)f2bf(v[0]) | ((uint32_t)f2bf(v[1]) << 16);
    uint32_t hi = (uint32_t)f2bf(v[2]) | ((uint32_t)f2bf(v[3]) << 16);
    *(uint2*)(Sb + i) = make_uint2(lo, hi);
}

__global__ __launch_bounds__(BLOCK_T, 4) void mahal_kernel(
    const float* __restrict__ x, const float* __restrict__ xf,
    const unsigned short* __restrict__ Sb, float* __restrict__ out)
{
    __shared__ unsigned short ld[RPT * LDS_STRIDE]; // 8704 B
    __shared__ float psum[8 * RPT];                 // 512 B

    const int t    = threadIdx.x;
    const int w    = t >> 6;      // wave 0..7: owns S cols [w*32, w*32+32)
    const int lane = t & 63;
    const int lo4  = lane & 15;
    const int kg   = lane >> 4;   // k-group 0..3
    const int srow = t >> 5;      // staging row 0..15
    const int scol = (t & 31) * 8;
    const int blockRow0 = blockIdx.x * (NT * RPT);

    // ---- prologue: issue tiles 0 and 1 (depth-2; 4 insts each) ----
    f32x4 xs[2][2], fs[2][2];
    {
        const int g0 = (blockRow0 + srow) * D + scol;
        xs[0][0] = gload4f(x + g0);  xs[0][1] = gload4f(x + g0 + 4);
        fs[0][0] = gload4f(xf + g0); fs[0][1] = gload4f(xf + g0 + 4);
        const int g1 = (blockRow0 + RPT + srow) * D + scol;
        xs[1][0] = gload4f(x + g1);  xs[1][1] = gload4f(x + g1 + 4);
        fs[1][0] = gload4f(xf + g1); fs[1][1] = gload4f(xf + g1 + 4);
    }

    // ---- S fragments: bf16 plain loads -> AGPRs (proven rounds 8-9).
    // A-operand: A[i][k] = S[w*32 + nb*16 + i][k] (S symmetric).
    bf16x8 b0[8], b1[8];
    {
        const unsigned short* Sp = Sb + (w * 32 + lo4) * D + kg * 8;
        #pragma unroll
        for (int kb = 0; kb < 8; ++kb) {
            b0[kb] = *(const bf16x8*)(Sp + kb * 32);
            b1[kb] = *(const bf16x8*)(Sp + 16 * D + kb * 32);
        }
    }

    #pragma unroll
    for (int j = 0; j < NT; ++j) {
        const int bsel = j & 1;   // compile-time after unroll

        // counted wait: tile j's 4 insts retired; tile j+1's 4 stay in flight
        if (j < NT - 1) { asm volatile("s_waitcnt vmcnt(4)" ::: "memory"); }
        else            { asm volatile("s_waitcnt vmcnt(0)" ::: "memory"); }
        __builtin_amdgcn_sched_barrier(0);

        if (j > 0) {
            // all waves done with tile j-1 (LDS reads + psum writes retired)
            asm volatile("s_waitcnt lgkmcnt(0)" ::: "memory");
            __builtin_amdgcn_s_barrier();
            // combine tile j-1 partials while other waves convert
            if (t < RPT) {
                float s = 0.f;
                #pragma unroll
                for (int ww = 0; ww < 8; ++ww) s += psum[ww * RPT + t];
                out[blockRow0 + (j - 1) * RPT + t] = s;
            }
        }

        // ---- convert tile j -> bf16 delta in LDS ----
        {
            bf16x8 o;
            o[0] = (short)f2bf(xs[bsel][0][0] - fs[bsel][0][0]);
            o[1] = (short)f2bf(xs[bsel][0][1] - fs[bsel][0][1]);
            o[2] = (short)f2bf(xs[bsel][0][2] - fs[bsel][0][2]);
            o[3] = (short)f2bf(xs[bsel][0][3] - fs[bsel][0][3]);
            o[4] = (short)f2bf(xs[bsel][1][0] - fs[bsel][1][0]);
            o[5] = (short)f2bf(xs[bsel][1][1] - fs[bsel][1][1]);
            o[6] = (short)f2bf(xs[bsel][1][2] - fs[bsel][1][2]);
            o[7] = (short)f2bf(xs[bsel][1][3] - fs[bsel][1][3]);
            *(bf16x8*)(&ld[srow * LDS_STRIDE + scol]) = o;
        }

        // ---- re-stage this buffer with tile j+2 (same parity) ----
        if (j + 2 < NT) {
            const int g = (blockRow0 + (j + 2) * RPT + srow) * D + scol;
            xs[bsel][0] = gload4f(x + g);  xs[bsel][1] = gload4f(x + g + 4);
            fs[bsel][0] = gload4f(xf + g); fs[bsel][1] = gload4f(xf + g + 4);
        }

        // LDS writes visible; lgkmcnt only - prefetch stays in flight
        asm volatile("s_waitcnt lgkmcnt(0)" ::: "memory");
        __builtin_amdgcn_s_barrier();
        __builtin_amdgcn_sched_barrier(0);

        // ---- compute tile j: T^T for this wave's 32-col slice ----
        {
            f32x4 acc0 = (f32x4){0.f, 0.f, 0.f, 0.f};
            f32x4 acc1 = (f32x4){0.f, 0.f, 0.f, 0.f};
            const unsigned short* A = &ld[lo4 * LDS_STRIDE + kg * 8];
            #pragma unroll
            for (int kb = 0; kb < 8; ++kb) {
                bf16x8 a = *(const bf16x8*)(A + kb * 32);
                // swapped operands: D[i][r] = sum_k S[slice_i][k]*delta[row_r][k]
                acc0 = __builtin_amdgcn_mfma_f32_16x16x32_bf16(b0[kb], a, acc0, 0, 0, 0);
                acc1 = __builtin_amdgcn_mfma_f32_16x16x32_bf16(b1[kb], a, acc1, 0, 0, 0);
            }
            // lane lo4 = delta row; reg r of acc_nb = T[drow][w*32+nb*16+kg*4+r]
            const unsigned short* dr = &ld[lo4 * LDS_STRIDE + w * 32 + kg * 4];
            bf16x4 d0 = *(const bf16x4*)(dr);
            bf16x4 d1 = *(const bf16x4*)(dr + 16);
            float pr = 0.f;
            #pragma unroll
            for (int r = 0; r < 4; ++r) {
                pr += acc0[r] * bf2f((unsigned short)d0[r]);
                pr += acc1[r] * bf2f((unsigned short)d1[r]);
            }
            // reduce over the 4 k-groups holding the same delta row
            pr += __shfl_xor(pr, 16, 64);
            pr += __shfl_xor(pr, 32, 64);
            if (lane < 16)
                psum[w * RPT + lane] = pr;
        }
    }

    // ---- final tile's combine ----
    asm volatile("s_waitcnt lgkmcnt(0)" ::: "memory");
    __builtin_amdgcn_s_barrier();
    if (t < RPT) {
        float s = 0.f;
        #pragma unroll
        for (int ww = 0; ww < 8; ++ww) s += psum[ww * RPT + t];
        out[blockRow0 + (NT - 1) * RPT + t] = s;
    }
}

extern "C" void kernel_launch(void* const* d_in, const int* in_sizes, int n_in,
                              void* d_out, int out_size, void* d_ws, size_t ws_size,
                              hipStream_t stream) {
    const float* x  = (const float*)d_in[0];
    const float* xf = (const float*)d_in[1];
    const float* S  = (const float*)d_in[2];
    float* out = (float*)d_out;
    unsigned short* Sb = (unsigned short*)d_ws;  // 65536 * 2B = 128 KB scratch

    prep_S_kernel<<<(D * D) / (256 * 4), 256, 0, stream>>>(S, Sb);

    const int nRows = in_sizes[0] / D;                 // 65536
    const int nBlocks = nRows / (NT * RPT);            // 512
    mahal_kernel<<<nBlocks, BLOCK_T, 0, stream>>>(x, xf, Sb, out);
}